// Round 16
// baseline (84.632 us; speedup 1.0000x reference)
//
#include <hip/hip_runtime.h>
#include <hip/hip_bf16.h>
#include <stdint.h>

// B=8, N=1024, D_IN=D_OUT=512, H=8, DH=64, SCALE=8
// Round 16: r15 + bias register double-buffer done with STATIC indexing
// (named arrays swapped via macro; no lambda refs -> no scratch spill, per
// rule #20). Prefetch issued at iter top, consumed one full body later.

typedef __attribute__((ext_vector_type(4))) float f32x4;
typedef __attribute__((ext_vector_type(8))) short s16x8;
typedef __attribute__((ext_vector_type(4))) unsigned short u16x4;
typedef __attribute__((ext_vector_type(8))) unsigned short u16x8;

union FragAB { s16x8 v; u16x4 h[2]; unsigned u[4]; };

#define LOG2E 1.44269504089f
#define QSCALE (0.125f * LOG2E)

__device__ __forceinline__ unsigned short f2b(float f) {
  unsigned u = __builtin_bit_cast(unsigned, f);
  u = (u + 0x7FFFu + ((u >> 16) & 1u)) >> 16;  // RNE
  return (unsigned short)u;
}
__device__ __forceinline__ unsigned cvt_pk(float a, float b) {
  unsigned r;
  asm("v_cvt_pk_bf16_f32 %0, %1, %2" : "=v"(r) : "v"(a), "v"(b));
  return r;
}
// async global->LDS, 16B per lane; LDS dest = wave-uniform base + lane*16.
__device__ __forceinline__ void gl_lds16(const unsigned short* g, unsigned short* l) {
  __builtin_amdgcn_global_load_lds(
      (const __attribute__((address_space(1))) unsigned int*)(g),
      (__attribute__((address_space(3))) unsigned int*)(l), 16, 0, 0);
}

// ---------------- merged prep: x->bf16 (blocks 0..4095), W transpose (4096..4351)
__global__ __launch_bounds__(256) void prep_k(const float* __restrict__ x,
                                              unsigned short* __restrict__ xb,
                                              const float* __restrict__ W0,
                                              const float* __restrict__ W1,
                                              const float* __restrict__ W2,
                                              const float* __restrict__ W3,
                                              unsigned short* __restrict__ Wt) {
  __shared__ float ld[64][68];
  const int t = threadIdx.x;
  if (blockIdx.x < 4096) {
    int idx = blockIdx.x * 256 + t;
    f32x4 v = ((const f32x4*)x)[idx];
    u16x4 o;
#pragma unroll
    for (int j = 0; j < 4; j++) o[j] = f2b(v[j]);
    ((u16x4*)xb)[idx] = o;
    return;
  }
  const int bid2 = blockIdx.x - 4096;
  const int widx = bid2 >> 6;
  const int tile = bid2 & 63;
  const int trow = tile >> 3, tcol = tile & 7;
  const float* W = widx == 0 ? W0 : widx == 1 ? W1 : widx == 2 ? W2 : W3;
  const int r = t >> 2, cc = (t & 3) * 16;
  const float* src = W + (size_t)(trow * 64 + r) * 512 + tcol * 64 + cc;
#pragma unroll
  for (int u = 0; u < 4; u++)
    ((f32x4*)&ld[r][cc])[u] = ((const f32x4*)src)[u];
  __syncthreads();
  unsigned short* dst = Wt + ((size_t)widx << 18) + (size_t)(tcol * 64 + r) * 512 +
                        trow * 64 + cc;
#pragma unroll
  for (int u = 0; u < 4; u++) {
    u16x4 o;
#pragma unroll
    for (int e = 0; e < 4; e++) o[e] = f2b(ld[cc + u * 4 + e][r]);
    ((u16x4*)dst)[u] = o;
  }
}

// ---------------- fused QKV GEMM: global_load_lds staging, V^T epilogue ----------------
__global__ __launch_bounds__(256, 2) void gemm_qkv_k(const unsigned short* __restrict__ A,
                                                     const unsigned short* __restrict__ Bt,
                                                     const float* __restrict__ bq,
                                                     const float* __restrict__ bk,
                                                     const float* __restrict__ bv,
                                                     unsigned short* __restrict__ outp) {
  __shared__ unsigned short SM[2][2][128][32];
  const int tid = threadIdx.x;
  const int lane = tid & 63;
  const int w = tid >> 6;
  const int wm = w >> 1, wn = w & 1;
  const int g = lane >> 4, c = lane & 15;
  const int bn0 = (blockIdx.x % 12) * 128;
  const int bm0 = (blockIdx.x / 12) * 128;

  f32x4 acc[4][4];
#pragma unroll
  for (int i = 0; i < 4; i++)
#pragma unroll
    for (int j = 0; j < 4; j++) acc[i][j] = f32x4{0.f, 0.f, 0.f, 0.f};

  auto stage = [&](int buf, int kt) {
#pragma unroll
    for (int j = 0; j < 2; j++) {
      const int qb = (j * 4 + w) * 64;
      const int chunk = qb + lane;
      const int row = chunk >> 2, slot = chunk & 3;
      gl_lds16(A + (size_t)(bm0 + row) * 512 + kt * 32 + slot * 8,
               &SM[buf][0][0][0] + qb * 8);
      gl_lds16(Bt + (size_t)(bn0 + row) * 512 + kt * 32 + slot * 8,
               &SM[buf][1][0][0] + qb * 8);
    }
  };

  stage(0, 0);
  asm volatile("s_waitcnt vmcnt(0)" ::: "memory");
  __syncthreads();

  for (int kt = 0; kt < 16; ++kt) {
    const int cb = kt & 1;
    if (kt < 15) stage(cb ^ 1, kt + 1);

    FragAB af[4], bf[4];
#pragma unroll
    for (int mi = 0; mi < 4; mi++) {
      const u16x4* p = (const u16x4*)&SM[cb][0][wm * 64 + mi * 16 + c][g * 8];
      af[mi].h[0] = p[0]; af[mi].h[1] = p[1];
    }
#pragma unroll
    for (int ni = 0; ni < 4; ni++) {
      const u16x4* p = (const u16x4*)&SM[cb][1][wn * 64 + ni * 16 + c][g * 8];
      bf[ni].h[0] = p[0]; bf[ni].h[1] = p[1];
    }
    __builtin_amdgcn_s_setprio(1);
#pragma unroll
    for (int mi = 0; mi < 4; mi++)
#pragma unroll
      for (int ni = 0; ni < 4; ni++)
        acc[mi][ni] = __builtin_amdgcn_mfma_f32_16x16x32_bf16(af[mi].v, bf[ni].v,
                                                              acc[mi][ni], 0, 0, 0);
    __builtin_amdgcn_s_setprio(0);

    if (kt < 15) {
      asm volatile("s_waitcnt vmcnt(0)" ::: "memory");
      __syncthreads();
    }
  }

  __syncthreads();  // SM reusable as scratch

  const int qkv = (bn0 + wn * 64) >> 9;
  const float* bp = qkv == 0 ? bq : (qkv == 1 ? bk : bv);
  const float scale = qkv == 0 ? QSCALE : 1.0f;
  const int b = (bm0 + wm * 64) >> 10;
  const int nb = (bm0 + wm * 64) & 1023;

  if (qkv == 2) {
    unsigned short* T = &SM[0][0][0][0] + w * 2176;
    const int hh = ((bn0 + wn * 64) & 511) >> 6;
    unsigned short* dst = outp + ((size_t)2 << 22) + ((size_t)((b << 3) + hh) << 16) + nb;
#pragma unroll
    for (int r2 = 0; r2 < 2; r2++) {
#pragma unroll
      for (int ni2 = 0; ni2 < 2; ni2++) {
        const int ni = r2 * 2 + ni2;
        const int dloc = ni2 * 16 + c;
        const float bvv = bp[(bn0 + wn * 64 + ni * 16 + c) & 511];
#pragma unroll
        for (int mi = 0; mi < 4; mi++) {
          const int n = mi * 16 + g * 4;
          *(unsigned*)&T[dloc * 68 + n] =
              cvt_pk(acc[mi][ni][0] + bvv, acc[mi][ni][1] + bvv);
          *(unsigned*)&T[dloc * 68 + n + 2] =
              cvt_pk(acc[mi][ni][2] + bvv, acc[mi][ni][3] + bvv);
        }
      }
      asm volatile("s_waitcnt lgkmcnt(0)" ::: "memory");
#pragma unroll
      for (int r = 0; r < 8; r++) {
        const int dloc = r * 4 + g;
        const u16x4 v4 = *(const u16x4*)&T[dloc * 68 + c * 4];
        *(u16x4*)(dst + ((size_t)(r2 * 32 + dloc) << 10) + c * 4) = v4;
      }
      if (r2 == 0) asm volatile("s_waitcnt lgkmcnt(0)" ::: "memory");
    }
  } else {
#pragma unroll
    for (int mi = 0; mi < 4; mi++)
#pragma unroll
      for (int ni = 0; ni < 4; ni++) {
        const int c9 = (bn0 + wn * 64 + ni * 16 + c) & 511;
        const float bvv = bp[c9];
        const int hh = c9 >> 6, d = c9 & 63;
#pragma unroll
        for (int m = 0; m < 4; m++) {
          const int n = nb + mi * 16 + g * 4 + m;
          const float v = (acc[mi][ni][m] + bvv) * scale;
          outp[((size_t)qkv << 22) + ((size_t)((b << 3) + hh) << 16) +
               ((size_t)n << 6) + d] = f2b(v);
        }
      }
  }
}

// ---------------- output GEMM: 8 waves, global_load_lds staging ----------------
__global__ __launch_bounds__(512, 2) void gemm_o_k(const unsigned short* __restrict__ A,
                                                   const unsigned short* __restrict__ Bt,
                                                   const float* __restrict__ bias,
                                                   float* __restrict__ outp) {
  __shared__ unsigned short SM[2][2][128][32];
  const int tid = threadIdx.x;
  const int lane = tid & 63;
  const int w = tid >> 6;
  const int wm = w >> 1, wn = w & 1;
  const int g = lane >> 4, c = lane & 15;
  const int bn0 = (blockIdx.x & 3) * 128;
  const int bm0 = (blockIdx.x >> 2) * 128;

  f32x4 acc[2][4];
#pragma unroll
  for (int i = 0; i < 2; i++)
#pragma unroll
    for (int j = 0; j < 4; j++) acc[i][j] = f32x4{0.f, 0.f, 0.f, 0.f};

  auto stage = [&](int buf, int kt) {
    const int qb = w * 64;
    const int chunk = qb + lane;
    const int row = chunk >> 2, slot = chunk & 3;
    gl_lds16(A + (size_t)(bm0 + row) * 512 + kt * 32 + slot * 8,
             &SM[buf][0][0][0] + qb * 8);
    gl_lds16(Bt + (size_t)(bn0 + row) * 512 + kt * 32 + slot * 8,
             &SM[buf][1][0][0] + qb * 8);
  };

  stage(0, 0);
  asm volatile("s_waitcnt vmcnt(0)" ::: "memory");
  __syncthreads();

  for (int kt = 0; kt < 16; ++kt) {
    const int cb = kt & 1;
    if (kt < 15) stage(cb ^ 1, kt + 1);

    FragAB af[2], bf[4];
#pragma unroll
    for (int mi = 0; mi < 2; mi++) {
      const u16x4* p = (const u16x4*)&SM[cb][0][wm * 32 + mi * 16 + c][g * 8];
      af[mi].h[0] = p[0]; af[mi].h[1] = p[1];
    }
#pragma unroll
    for (int ni = 0; ni < 4; ni++) {
      const u16x4* p = (const u16x4*)&SM[cb][1][wn * 64 + ni * 16 + c][g * 8];
      bf[ni].h[0] = p[0]; bf[ni].h[1] = p[1];
    }
    __builtin_amdgcn_s_setprio(1);
#pragma unroll
    for (int mi = 0; mi < 2; mi++)
#pragma unroll
      for (int ni = 0; ni < 4; ni++)
        acc[mi][ni] = __builtin_amdgcn_mfma_f32_16x16x32_bf16(af[mi].v, bf[ni].v,
                                                              acc[mi][ni], 0, 0, 0);
    __builtin_amdgcn_s_setprio(0);

    if (kt < 15) {
      asm volatile("s_waitcnt vmcnt(0)" ::: "memory");
      __syncthreads();
    }
  }

#pragma unroll
  for (int mi = 0; mi < 2; mi++) {
#pragma unroll
    for (int ni = 0; ni < 4; ni++) {
      const int col = bn0 + wn * 64 + ni * 16 + c;
      const float bv = bias[col];
#pragma unroll
      for (int m = 0; m < 4; m++) {
        const int row = bm0 + wm * 32 + mi * 16 + g * 4 + m;
        outp[(size_t)row * 512 + col] = acc[mi][ni][m] + bv;
      }
    }
  }
}

// ---------------- flash attention: swapped-QK, bias reg dbuf (static) ----------------
__global__ __launch_bounds__(256, 2) void attn_k(const unsigned short* __restrict__ Qb,
                                                 const unsigned short* __restrict__ Kb,
                                                 const unsigned short* __restrict__ Vt,
                                                 const float* __restrict__ pos_bias,
                                                 unsigned short* __restrict__ ao) {
  __shared__ unsigned short Klds[2][64][68];
  __shared__ unsigned short Vtlds[2][64][68];  // [d][kv_row]
  __shared__ unsigned short Plds[4][32][68];   // [wave][q-local][kv]

  const int tid = threadIdx.x;
  const int lane = tid & 63;
  const int w = tid >> 6;
  const int g = lane >> 4, c = lane & 15;
  const int L = blockIdx.x;
  const int qt = L >> 6;
  const int bh = (L & 7) + 8 * ((L >> 3) & 7);  // XCD(L)=L%8 -> one head/XCD
  const int h = bh & 7;
  const size_t bhq = (size_t)bh << 16;
  const int q0 = qt * 128 + w * 32;

  FragAB aq[2][2];
#pragma unroll
  for (int mi = 0; mi < 2; mi++)
#pragma unroll
    for (int kk = 0; kk < 2; kk++) {
      const u16x4* p = (const u16x4*)(Qb + bhq + ((size_t)(q0 + mi * 16 + c) << 6) +
                                      kk * 32 + g * 8);
      aq[mi][kk].h[0] = p[0]; aq[mi][kk].h[1] = p[1];
    }

  f32x4 acco[2][4];
#pragma unroll
  for (int mi = 0; mi < 2; mi++)
#pragma unroll
    for (int nd = 0; nd < 4; nd++) acco[mi][nd] = f32x4{0.f, 0.f, 0.f, 0.f};
  float lsum[2] = {0.f, 0.f};

  const int srow = tid >> 2;
  const int scol = (tid & 3) * 16;
  const unsigned short* pK = Kb + bhq + ((size_t)srow << 6) + scol;
  const unsigned short* pV = Vt + bhq + ((size_t)srow << 10) + scol;

  u16x8 kr0, kr1, vr0, vr1;
  auto stageLoad = [&](int k0n) {
    const u16x8* a = (const u16x8*)(pK + ((size_t)k0n << 6));
    kr0 = a[0]; kr1 = a[1];
    const u16x8* bb = (const u16x8*)(pV + k0n);
    vr0 = bb[0]; vr1 = bb[1];
  };
  auto stageWrite = [&](int b) {
    *(u16x8*)&Klds[b][srow][scol] = kr0;
    *(u16x8*)&Klds[b][srow][scol + 8] = kr1;
    *(u16x8*)&Vtlds[b][srow][scol] = vr0;
    *(u16x8*)&Vtlds[b][srow][scol + 8] = vr1;
  };

  const float* pbB = pos_bias + ((size_t)h << 20) + ((size_t)(q0 + c) << 10) + 4 * g;

  // bias register double-buffer, STATIC indexing: two named arrays, macro body.
  f32x4 pbA0[4], pbA1[4], pbB0[4], pbB1[4];
#pragma unroll
  for (int ni = 0; ni < 4; ni++) {
    pbA0[ni] = *(const f32x4*)(pbB + 16 * ni);            // mi=0, tile 0
    pbA1[ni] = *(const f32x4*)(pbB + (1 << 14) + 16 * ni); // mi=1, tile 0
  }

  stageLoad(0);
  stageWrite(0);
  __syncthreads();

#define ATTN_BODY(KT, PU0, PU1, PN0, PN1, PREK)                                   \
  {                                                                               \
    const int buf = (KT) & 1;                                                     \
    if ((KT) < 15) stageLoad(((KT) << 6) + 64);                                   \
    _Pragma("unroll") for (int ni = 0; ni < 4; ni++) {                            \
      PN0[ni] = *(const f32x4*)(pbB + (PREK) + 16 * ni);                          \
      PN1[ni] = *(const f32x4*)(pbB + (1 << 14) + (PREK) + 16 * ni);              \
    }                                                                             \
    FragAB bk[4][2];                                                              \
    _Pragma("unroll") for (int ni = 0; ni < 4; ni++)                              \
      _Pragma("unroll") for (int kk = 0; kk < 2; kk++) {                          \
        const u16x4* p = (const u16x4*)&Klds[buf][ni * 16 + c][kk * 32 + g * 8];  \
        bk[ni][kk].h[0] = p[0]; bk[ni][kk].h[1] = p[1];                           \
      }                                                                           \
    f32x4 sT[2][4];                                                               \
    __builtin_amdgcn_s_setprio(1);                                                \
    _Pragma("unroll") for (int mi = 0; mi < 2; mi++)                              \
      _Pragma("unroll") for (int ni = 0; ni < 4; ni++) {                          \
        f32x4 s = f32x4{0.f, 0.f, 0.f, 0.f};                                      \
        s = __builtin_amdgcn_mfma_f32_16x16x32_bf16(bk[ni][0].v, aq[mi][0].v, s,  \
                                                    0, 0, 0);                     \
        s = __builtin_amdgcn_mfma_f32_16x16x32_bf16(bk[ni][1].v, aq[mi][1].v, s,  \
                                                    0, 0, 0);                     \
        sT[mi][ni] = s;                                                           \
      }                                                                           \
    __builtin_amdgcn_s_setprio(0);                                                \
    FragAB vb2[4][2];                                                             \
    _Pragma("unroll") for (int nd = 0; nd < 4; nd++)                              \
      _Pragma("unroll") for (int kc = 0; kc < 2; kc++) {                          \
        const u16x4* p = (const u16x4*)&Vtlds[buf][nd * 16 + c][kc * 32 + g * 8]; \
        vb2[nd][kc].h[0] = p[0]; vb2[nd][kc].h[1] = p[1];                         \
      }                                                                           \
    _Pragma("unroll") for (int ni = 0; ni < 4; ni++) {                            \
      const float a0 = __builtin_amdgcn_exp2f(fmaf(PU0[ni][0], LOG2E, sT[0][ni][0])); \
      const float a1 = __builtin_amdgcn_exp2f(fmaf(PU0[ni][1], LOG2E, sT[0][ni][1])); \
      const float a2 = __builtin_amdgcn_exp2f(fmaf(PU0[ni][2], LOG2E, sT[0][ni][2])); \
      const float a3 = __builtin_amdgcn_exp2f(fmaf(PU0[ni][3], LOG2E, sT[0][ni][3])); \
      lsum[0] += (a0 + a1) + (a2 + a3);                                           \
      uint2 t0; t0.x = cvt_pk(a0, a1); t0.y = cvt_pk(a2, a3);                     \
      *(uint2*)&Plds[w][c][16 * ni + 4 * g] = t0;                                 \
      const float b0 = __builtin_amdgcn_exp2f(fmaf(PU1[ni][0], LOG2E, sT[1][ni][0])); \
      const float b1 = __builtin_amdgcn_exp2f(fmaf(PU1[ni][1], LOG2E, sT[1][ni][1])); \
      const float b2 = __builtin_amdgcn_exp2f(fmaf(PU1[ni][2], LOG2E, sT[1][ni][2])); \
      const float b3 = __builtin_amdgcn_exp2f(fmaf(PU1[ni][3], LOG2E, sT[1][ni][3])); \
      lsum[1] += (b0 + b1) + (b2 + b3);                                           \
      uint2 t1; t1.x = cvt_pk(b0, b1); t1.y = cvt_pk(b2, b3);                     \
      *(uint2*)&Plds[w][16 + c][16 * ni + 4 * g] = t1;                            \
    }                                                                             \
    asm volatile("s_waitcnt lgkmcnt(0)" ::: "memory");                            \
    FragAB paf[2][2];                                                             \
    _Pragma("unroll") for (int mi = 0; mi < 2; mi++)                              \
      _Pragma("unroll") for (int kc = 0; kc < 2; kc++) {                          \
        const u16x4* p = (const u16x4*)&Plds[w][mi * 16 + c][kc * 32 + g * 8];    \
        paf[mi][kc].h[0] = p[0]; paf[mi][kc].h[1] = p[1];                         \
      }                                                                           \
    __builtin_amdgcn_s_setprio(1);                                                \
    _Pragma("unroll") for (int mi = 0; mi < 2; mi++)                              \
      _Pragma("unroll") for (int nd = 0; nd < 4; nd++) {                          \
        acco[mi][nd] = __builtin_amdgcn_mfma_f32_16x16x32_bf16(                   \
            paf[mi][0].v, vb2[nd][0].v, acco[mi][nd], 0, 0, 0);                   \
        acco[mi][nd] = __builtin_amdgcn_mfma_f32_16x16x32_bf16(                   \
            paf[mi][1].v, vb2[nd][1].v, acco[mi][nd], 0, 0, 0);                   \
      }                                                                           \
    __builtin_amdgcn_s_setprio(0);                                                \
    if ((KT) < 15) {                                                              \
      stageWrite(buf ^ 1);                                                        \
      __syncthreads();                                                            \
    }                                                                             \
  }

  for (int kt2 = 0; kt2 < 16; kt2 += 2) {
    const int prek0 = (kt2 < 14) ? ((kt2 + 1) << 6) : 960;  // bias for kt2+1
    const int prek1 = (kt2 < 14) ? ((kt2 + 2) << 6) : 960;  // bias for kt2+2 (clamped)
    ATTN_BODY(kt2, pbA0, pbA1, pbB0, pbB1, prek0);
    ATTN_BODY(kt2 + 1, pbB0, pbB1, pbA0, pbA1, prek1);
  }
#undef ATTN_BODY

  const int b = bh >> 3;
#pragma unroll
  for (int mi = 0; mi < 2; mi++) {
    float l = lsum[mi];
    l += __shfl_xor(l, 16);
    l += __shfl_xor(l, 32);
    const float inv_c = 1.f / l;
#pragma unroll
    for (int m = 0; m < 4; m++) {
      const float invm = __shfl(inv_c, g * 4 + m);
      const int n = q0 + mi * 16 + g * 4 + m;
#pragma unroll
      for (int nd = 0; nd < 4; nd++) {
        ao[((size_t)(b * 1024 + n) << 9) + h * 64 + nd * 16 + c] =
            f2b(acco[mi][nd][m] * invm);
      }
    }
  }
}

// ---------------- launch ----------------
extern "C" void kernel_launch(void* const* d_in, const int* in_sizes, int n_in,
                              void* d_out, int out_size, void* d_ws, size_t ws_size,
                              hipStream_t stream) {
  (void)in_sizes; (void)n_in; (void)out_size; (void)ws_size;
  const float* x  = (const float*)d_in[0];
  const float* Wq = (const float*)d_in[1];
  const float* bq = (const float*)d_in[2];
  const float* Wk = (const float*)d_in[3];
  const float* bk = (const float*)d_in[4];
  const float* Wv = (const float*)d_in[5];
  const float* bv = (const float*)d_in[6];
  const float* Wo = (const float*)d_in[7];
  const float* bo = (const float*)d_in[8];
  const float* pbias = (const float*)d_in[9];

  char* p = (char*)d_ws;
  unsigned short* xb  = (unsigned short*)p; p += (size_t)8192 * 512 * 2;
  unsigned short* WT  = (unsigned short*)p; p += (size_t)4 * 512 * 512 * 2;
  unsigned short* Qb  = (unsigned short*)p; p += (size_t)3 * 64 * 1024 * 64 * 2;
  unsigned short* AO  = (unsigned short*)p;

  unsigned short* WoT = WT + (size_t)3 * 512 * 512;
  unsigned short* Kb  = Qb + (size_t)64 * 1024 * 64;
  unsigned short* Vb  = Kb + (size_t)64 * 1024 * 64;  // V^T slab [bh][d][n]

  prep_k<<<4352, 256, 0, stream>>>(x, xb, Wq, Wk, Wv, Wo, WT);
  gemm_qkv_k<<<768, 256, 0, stream>>>(xb, WT, bq, bk, bv, Qb);
  attn_k<<<512, 256, 0, stream>>>(Qb, Kb, Vb, pbias, AO);
  gemm_o_k<<<256, 512, 0, stream>>>(AO, WoT, bo, (float*)d_out);
}

// Round 17
// 81.200 us; speedup vs baseline: 1.0423x; 1.0423x over previous
//
#include <hip/hip_runtime.h>
#include <hip/hip_bf16.h>
#include <stdint.h>

// B=8, N=1024, D_IN=D_OUT=512, H=8, DH=64, SCALE=8
// FINAL (= r15, measured optimum 81.2 us):
//  - prep: merged x->bf16 + LDS-tiled W transpose
//  - gemm_qkv: fused N=1536 GEMM, global_load_lds staging (m97 recipe),
//    head-split Q/K out, V written TRANSPOSED via LDS-scratch epilogue,
//    Q pre-scaled by 0.125*log2e
//  - attn: swapped-operand QK^T (S^T layout -> vectorized bias loads),
//    max-free softmax with deferred denominator, K/V LDS double-buffer,
//    in-register P via cvt_pk, XCD head-affinity block remap
//  - gemm_o: 8-wave blocks, global_load_lds staging
// Parameter space around this point is fully explored (r6-r16); every
// perturbation was null or negative. Further gains need a co-designed
// 8-phase/counted-vmcnt restructure.

typedef __attribute__((ext_vector_type(4))) float f32x4;
typedef __attribute__((ext_vector_type(8))) short s16x8;
typedef __attribute__((ext_vector_type(4))) unsigned short u16x4;
typedef __attribute__((ext_vector_type(8))) unsigned short u16x8;

union FragAB { s16x8 v; u16x4 h[2]; unsigned u[4]; };

#define LOG2E 1.44269504089f
#define QSCALE (0.125f * LOG2E)

__device__ __forceinline__ unsigned short f2b(float f) {
  unsigned u = __builtin_bit_cast(unsigned, f);
  u = (u + 0x7FFFu + ((u >> 16) & 1u)) >> 16;  // RNE
  return (unsigned short)u;
}
__device__ __forceinline__ unsigned cvt_pk(float a, float b) {
  unsigned r;
  asm("v_cvt_pk_bf16_f32 %0, %1, %2" : "=v"(r) : "v"(a), "v"(b));
  return r;
}
// async global->LDS, 16B per lane; LDS dest = wave-uniform base + lane*16.
__device__ __forceinline__ void gl_lds16(const unsigned short* g, unsigned short* l) {
  __builtin_amdgcn_global_load_lds(
      (const __attribute__((address_space(1))) unsigned int*)(g),
      (__attribute__((address_space(3))) unsigned int*)(l), 16, 0, 0);
}

// ---------------- merged prep: x->bf16 (blocks 0..4095), W transpose (4096..4351)
__global__ __launch_bounds__(256) void prep_k(const float* __restrict__ x,
                                              unsigned short* __restrict__ xb,
                                              const float* __restrict__ W0,
                                              const float* __restrict__ W1,
                                              const float* __restrict__ W2,
                                              const float* __restrict__ W3,
                                              unsigned short* __restrict__ Wt) {
  __shared__ float ld[64][68];
  const int t = threadIdx.x;
  if (blockIdx.x < 4096) {
    int idx = blockIdx.x * 256 + t;
    f32x4 v = ((const f32x4*)x)[idx];
    u16x4 o;
#pragma unroll
    for (int j = 0; j < 4; j++) o[j] = f2b(v[j]);
    ((u16x4*)xb)[idx] = o;
    return;
  }
  const int bid2 = blockIdx.x - 4096;
  const int widx = bid2 >> 6;
  const int tile = bid2 & 63;
  const int trow = tile >> 3, tcol = tile & 7;
  const float* W = widx == 0 ? W0 : widx == 1 ? W1 : widx == 2 ? W2 : W3;
  const int r = t >> 2, cc = (t & 3) * 16;
  const float* src = W + (size_t)(trow * 64 + r) * 512 + tcol * 64 + cc;
#pragma unroll
  for (int u = 0; u < 4; u++)
    ((f32x4*)&ld[r][cc])[u] = ((const f32x4*)src)[u];
  __syncthreads();
  unsigned short* dst = Wt + ((size_t)widx << 18) + (size_t)(tcol * 64 + r) * 512 +
                        trow * 64 + cc;
#pragma unroll
  for (int u = 0; u < 4; u++) {
    u16x4 o;
#pragma unroll
    for (int e = 0; e < 4; e++) o[e] = f2b(ld[cc + u * 4 + e][r]);
    ((u16x4*)dst)[u] = o;
  }
}

// ---------------- fused QKV GEMM: global_load_lds staging, V^T epilogue ----------------
__global__ __launch_bounds__(256, 2) void gemm_qkv_k(const unsigned short* __restrict__ A,
                                                     const unsigned short* __restrict__ Bt,
                                                     const float* __restrict__ bq,
                                                     const float* __restrict__ bk,
                                                     const float* __restrict__ bv,
                                                     unsigned short* __restrict__ outp) {
  __shared__ unsigned short SM[2][2][128][32];  // [buf][A/B][row][k] linear, 32KB
  const int tid = threadIdx.x;
  const int lane = tid & 63;
  const int w = tid >> 6;
  const int wm = w >> 1, wn = w & 1;
  const int g = lane >> 4, c = lane & 15;
  const int bn0 = (blockIdx.x % 12) * 128;
  const int bm0 = (blockIdx.x / 12) * 128;

  f32x4 acc[4][4];
#pragma unroll
  for (int i = 0; i < 4; i++)
#pragma unroll
    for (int j = 0; j < 4; j++) acc[i][j] = f32x4{0.f, 0.f, 0.f, 0.f};

  auto stage = [&](int buf, int kt) {
#pragma unroll
    for (int j = 0; j < 2; j++) {
      const int qb = (j * 4 + w) * 64;
      const int chunk = qb + lane;
      const int row = chunk >> 2, slot = chunk & 3;
      gl_lds16(A + (size_t)(bm0 + row) * 512 + kt * 32 + slot * 8,
               &SM[buf][0][0][0] + qb * 8);
      gl_lds16(Bt + (size_t)(bn0 + row) * 512 + kt * 32 + slot * 8,
               &SM[buf][1][0][0] + qb * 8);
    }
  };

  stage(0, 0);
  asm volatile("s_waitcnt vmcnt(0)" ::: "memory");
  __syncthreads();

  for (int kt = 0; kt < 16; ++kt) {
    const int cb = kt & 1;
    if (kt < 15) stage(cb ^ 1, kt + 1);

    FragAB af[4], bf[4];
#pragma unroll
    for (int mi = 0; mi < 4; mi++) {
      const u16x4* p = (const u16x4*)&SM[cb][0][wm * 64 + mi * 16 + c][g * 8];
      af[mi].h[0] = p[0]; af[mi].h[1] = p[1];
    }
#pragma unroll
    for (int ni = 0; ni < 4; ni++) {
      const u16x4* p = (const u16x4*)&SM[cb][1][wn * 64 + ni * 16 + c][g * 8];
      bf[ni].h[0] = p[0]; bf[ni].h[1] = p[1];
    }
    __builtin_amdgcn_s_setprio(1);
#pragma unroll
    for (int mi = 0; mi < 4; mi++)
#pragma unroll
      for (int ni = 0; ni < 4; ni++)
        acc[mi][ni] = __builtin_amdgcn_mfma_f32_16x16x32_bf16(af[mi].v, bf[ni].v,
                                                              acc[mi][ni], 0, 0, 0);
    __builtin_amdgcn_s_setprio(0);

    if (kt < 15) {
      asm volatile("s_waitcnt vmcnt(0)" ::: "memory");
      __syncthreads();
    }
  }

  __syncthreads();  // all frag reads done; SM reusable as scratch

  const int qkv = (bn0 + wn * 64) >> 9;  // wave-uniform: 0=Q 1=K 2=V
  const float* bp = qkv == 0 ? bq : (qkv == 1 ? bk : bv);
  const float scale = qkv == 0 ? QSCALE : 1.0f;
  const int b = (bm0 + wm * 64) >> 10;
  const int nb = (bm0 + wm * 64) & 1023;

  if (qkv == 2) {
    // V: transpose 64x64 wave tile via per-wave LDS scratch, then
    // 128B-contiguous stores of Vt[bh][d][n].
    unsigned short* T = &SM[0][0][0][0] + w * 2176;
    const int hh = ((bn0 + wn * 64) & 511) >> 6;
    unsigned short* dst = outp + ((size_t)2 << 22) + ((size_t)((b << 3) + hh) << 16) + nb;
#pragma unroll
    for (int r2 = 0; r2 < 2; r2++) {
#pragma unroll
      for (int ni2 = 0; ni2 < 2; ni2++) {
        const int ni = r2 * 2 + ni2;
        const int dloc = ni2 * 16 + c;
        const float bvv = bp[(bn0 + wn * 64 + ni * 16 + c) & 511];
#pragma unroll
        for (int mi = 0; mi < 4; mi++) {
          const int n = mi * 16 + g * 4;
          *(unsigned*)&T[dloc * 68 + n] =
              cvt_pk(acc[mi][ni][0] + bvv, acc[mi][ni][1] + bvv);
          *(unsigned*)&T[dloc * 68 + n + 2] =
              cvt_pk(acc[mi][ni][2] + bvv, acc[mi][ni][3] + bvv);
        }
      }
      asm volatile("s_waitcnt lgkmcnt(0)" ::: "memory");
#pragma unroll
      for (int r = 0; r < 8; r++) {
        const int dloc = r * 4 + g;
        const u16x4 v4 = *(const u16x4*)&T[dloc * 68 + c * 4];
        *(u16x4*)(dst + ((size_t)(r2 * 32 + dloc) << 10) + c * 4) = v4;
      }
      if (r2 == 0) asm volatile("s_waitcnt lgkmcnt(0)" ::: "memory");
    }
  } else {
#pragma unroll
    for (int mi = 0; mi < 4; mi++)
#pragma unroll
      for (int ni = 0; ni < 4; ni++) {
        const int c9 = (bn0 + wn * 64 + ni * 16 + c) & 511;
        const float bvv = bp[c9];
        const int hh = c9 >> 6, d = c9 & 63;
#pragma unroll
        for (int m = 0; m < 4; m++) {
          const int n = nb + mi * 16 + g * 4 + m;
          const float v = (acc[mi][ni][m] + bvv) * scale;
          outp[((size_t)qkv << 22) + ((size_t)((b << 3) + hh) << 16) +
               ((size_t)n << 6) + d] = f2b(v);
        }
      }
  }
}

// ---------------- output GEMM: 8 waves, global_load_lds staging ----------------
__global__ __launch_bounds__(512, 2) void gemm_o_k(const unsigned short* __restrict__ A,
                                                   const unsigned short* __restrict__ Bt,
                                                   const float* __restrict__ bias,
                                                   float* __restrict__ outp) {
  __shared__ unsigned short SM[2][2][128][32];
  const int tid = threadIdx.x;
  const int lane = tid & 63;
  const int w = tid >> 6;               // 0..7
  const int wm = w >> 1, wn = w & 1;    // 4x2 wave grid; wave tile 32x64
  const int g = lane >> 4, c = lane & 15;
  const int bn0 = (blockIdx.x & 3) * 128;
  const int bm0 = (blockIdx.x >> 2) * 128;

  f32x4 acc[2][4];
#pragma unroll
  for (int i = 0; i < 2; i++)
#pragma unroll
    for (int j = 0; j < 4; j++) acc[i][j] = f32x4{0.f, 0.f, 0.f, 0.f};

  auto stage = [&](int buf, int kt) {
    const int qb = w * 64;
    const int chunk = qb + lane;
    const int row = chunk >> 2, slot = chunk & 3;
    gl_lds16(A + (size_t)(bm0 + row) * 512 + kt * 32 + slot * 8,
             &SM[buf][0][0][0] + qb * 8);
    gl_lds16(Bt + (size_t)(bn0 + row) * 512 + kt * 32 + slot * 8,
             &SM[buf][1][0][0] + qb * 8);
  };

  stage(0, 0);
  asm volatile("s_waitcnt vmcnt(0)" ::: "memory");
  __syncthreads();

  for (int kt = 0; kt < 16; ++kt) {
    const int cb = kt & 1;
    if (kt < 15) stage(cb ^ 1, kt + 1);

    FragAB af[2], bf[4];
#pragma unroll
    for (int mi = 0; mi < 2; mi++) {
      const u16x4* p = (const u16x4*)&SM[cb][0][wm * 32 + mi * 16 + c][g * 8];
      af[mi].h[0] = p[0]; af[mi].h[1] = p[1];
    }
#pragma unroll
    for (int ni = 0; ni < 4; ni++) {
      const u16x4* p = (const u16x4*)&SM[cb][1][wn * 64 + ni * 16 + c][g * 8];
      bf[ni].h[0] = p[0]; bf[ni].h[1] = p[1];
    }
    __builtin_amdgcn_s_setprio(1);
#pragma unroll
    for (int mi = 0; mi < 2; mi++)
#pragma unroll
      for (int ni = 0; ni < 4; ni++)
        acc[mi][ni] = __builtin_amdgcn_mfma_f32_16x16x32_bf16(af[mi].v, bf[ni].v,
                                                              acc[mi][ni], 0, 0, 0);
    __builtin_amdgcn_s_setprio(0);

    if (kt < 15) {
      asm volatile("s_waitcnt vmcnt(0)" ::: "memory");
      __syncthreads();
    }
  }

#pragma unroll
  for (int mi = 0; mi < 2; mi++) {
#pragma unroll
    for (int ni = 0; ni < 4; ni++) {
      const int col = bn0 + wn * 64 + ni * 16 + c;
      const float bv = bias[col];
#pragma unroll
      for (int m = 0; m < 4; m++) {
        const int row = bm0 + wm * 32 + mi * 16 + g * 4 + m;
        outp[(size_t)row * 512 + col] = acc[mi][ni][m] + bv;
      }
    }
  }
}

// ---------------- flash attention: swapped-QK, 32 q/wave, V^T input ----------------
__global__ __launch_bounds__(256, 2) void attn_k(const unsigned short* __restrict__ Qb,
                                                 const unsigned short* __restrict__ Kb,
                                                 const unsigned short* __restrict__ Vt,
                                                 const float* __restrict__ pos_bias,
                                                 unsigned short* __restrict__ ao) {
  __shared__ unsigned short Klds[2][64][68];
  __shared__ unsigned short Vtlds[2][64][68];  // [d][kv_row]
  __shared__ unsigned short Plds[4][32][68];   // [wave][q-local][kv]

  const int tid = threadIdx.x;
  const int lane = tid & 63;
  const int w = tid >> 6;
  const int g = lane >> 4, c = lane & 15;
  const int L = blockIdx.x;
  const int qt = L >> 6;
  const int bh = (L & 7) + 8 * ((L >> 3) & 7);  // XCD(L)=L%8 -> one head/XCD
  const int h = bh & 7;
  const size_t bhq = (size_t)bh << 16;
  const int q0 = qt * 128 + w * 32;

  FragAB aq[2][2];
#pragma unroll
  for (int mi = 0; mi < 2; mi++)
#pragma unroll
    for (int kk = 0; kk < 2; kk++) {
      const u16x4* p = (const u16x4*)(Qb + bhq + ((size_t)(q0 + mi * 16 + c) << 6) +
                                      kk * 32 + g * 8);
      aq[mi][kk].h[0] = p[0]; aq[mi][kk].h[1] = p[1];
    }

  f32x4 acco[2][4];
#pragma unroll
  for (int mi = 0; mi < 2; mi++)
#pragma unroll
    for (int nd = 0; nd < 4; nd++) acco[mi][nd] = f32x4{0.f, 0.f, 0.f, 0.f};
  float lsum[2] = {0.f, 0.f};

  const int srow = tid >> 2;
  const int scol = (tid & 3) * 16;
  const unsigned short* pK = Kb + bhq + ((size_t)srow << 6) + scol;
  const unsigned short* pV = Vt + bhq + ((size_t)srow << 10) + scol;

  u16x8 kr0, kr1, vr0, vr1;
  auto stageLoad = [&](int k0n) {
    const u16x8* a = (const u16x8*)(pK + ((size_t)k0n << 6));
    kr0 = a[0]; kr1 = a[1];
    const u16x8* bb = (const u16x8*)(pV + k0n);
    vr0 = bb[0]; vr1 = bb[1];
  };
  auto stageWrite = [&](int b) {
    *(u16x8*)&Klds[b][srow][scol] = kr0;
    *(u16x8*)&Klds[b][srow][scol + 8] = kr1;
    *(u16x8*)&Vtlds[b][srow][scol] = vr0;
    *(u16x8*)&Vtlds[b][srow][scol + 8] = vr1;
  };

  const float* pbB = pos_bias + ((size_t)h << 20) + ((size_t)(q0 + c) << 10) + 4 * g;

  stageLoad(0);
  stageWrite(0);
  __syncthreads();

  for (int kt = 0; kt < 16; ++kt) {
    const int buf = kt & 1;
    const int k0 = kt << 6;
    if (kt < 15) stageLoad(k0 + 64);

    f32x4 pb[2][4];
#pragma unroll
    for (int mi = 0; mi < 2; mi++)
#pragma unroll
      for (int ni = 0; ni < 4; ni++)
        pb[mi][ni] = *(const f32x4*)(pbB + (mi << 14) + k0 + 16 * ni);

    // S^T = K @ Q^T
    FragAB bk[4][2];
#pragma unroll
    for (int ni = 0; ni < 4; ni++)
#pragma unroll
      for (int kk = 0; kk < 2; kk++) {
        const u16x4* p = (const u16x4*)&Klds[buf][ni * 16 + c][kk * 32 + g * 8];
        bk[ni][kk].h[0] = p[0]; bk[ni][kk].h[1] = p[1];
      }
    f32x4 sT[2][4];
    __builtin_amdgcn_s_setprio(1);
#pragma unroll
    for (int mi = 0; mi < 2; mi++)
#pragma unroll
      for (int ni = 0; ni < 4; ni++) {
        f32x4 s = f32x4{0.f, 0.f, 0.f, 0.f};
        s = __builtin_amdgcn_mfma_f32_16x16x32_bf16(bk[ni][0].v, aq[mi][0].v, s, 0, 0, 0);
        s = __builtin_amdgcn_mfma_f32_16x16x32_bf16(bk[ni][1].v, aq[mi][1].v, s, 0, 0, 0);
        sT[mi][ni] = s;
      }
    __builtin_amdgcn_s_setprio(0);

    // V-frag reads issued early: latency hides under softmax VALU
    FragAB vb2[4][2];
#pragma unroll
    for (int nd = 0; nd < 4; nd++)
#pragma unroll
      for (int kc = 0; kc < 2; kc++) {
        const u16x4* p = (const u16x4*)&Vtlds[buf][nd * 16 + c][kc * 32 + g * 8];
        vb2[nd][kc].h[0] = p[0]; vb2[nd][kc].h[1] = p[1];
      }

    // p = exp2(s + bias*log2e); pack via v_cvt_pk_bf16_f32
#pragma unroll
    for (int mi = 0; mi < 2; mi++)
#pragma unroll
      for (int ni = 0; ni < 4; ni++) {
        const float p0 = __builtin_amdgcn_exp2f(fmaf(pb[mi][ni][0], LOG2E, sT[mi][ni][0]));
        const float p1 = __builtin_amdgcn_exp2f(fmaf(pb[mi][ni][1], LOG2E, sT[mi][ni][1]));
        const float p2 = __builtin_amdgcn_exp2f(fmaf(pb[mi][ni][2], LOG2E, sT[mi][ni][2]));
        const float p3 = __builtin_amdgcn_exp2f(fmaf(pb[mi][ni][3], LOG2E, sT[mi][ni][3]));
        lsum[mi] += (p0 + p1) + (p2 + p3);
        uint2 two;
        two.x = cvt_pk(p0, p1);
        two.y = cvt_pk(p2, p3);
        *(uint2*)&Plds[w][mi * 16 + c][16 * ni + 4 * g] = two;
      }

    asm volatile("s_waitcnt lgkmcnt(0)" ::: "memory");

    // O += P @ V
    FragAB paf[2][2];
#pragma unroll
    for (int mi = 0; mi < 2; mi++)
#pragma unroll
      for (int kc = 0; kc < 2; kc++) {
        const u16x4* p = (const u16x4*)&Plds[w][mi * 16 + c][kc * 32 + g * 8];
        paf[mi][kc].h[0] = p[0]; paf[mi][kc].h[1] = p[1];
      }
    __builtin_amdgcn_s_setprio(1);
#pragma unroll
    for (int mi = 0; mi < 2; mi++)
#pragma unroll
      for (int nd = 0; nd < 4; nd++) {
        acco[mi][nd] = __builtin_amdgcn_mfma_f32_16x16x32_bf16(paf[mi][0].v, vb2[nd][0].v,
                                                               acco[mi][nd], 0, 0, 0);
        acco[mi][nd] = __builtin_amdgcn_mfma_f32_16x16x32_bf16(paf[mi][1].v, vb2[nd][1].v,
                                                               acco[mi][nd], 0, 0, 0);
      }
    __builtin_amdgcn_s_setprio(0);

    if (kt < 15) {
      stageWrite(buf ^ 1);
      __syncthreads();
    }
  }

  const int b = bh >> 3;
#pragma unroll
  for (int mi = 0; mi < 2; mi++) {
    float l = lsum[mi];
    l += __shfl_xor(l, 16);
    l += __shfl_xor(l, 32);
    const float inv_c = 1.f / l;
#pragma unroll
    for (int m = 0; m < 4; m++) {
      const float invm = __shfl(inv_c, g * 4 + m);
      const int n = q0 + mi * 16 + g * 4 + m;
#pragma unroll
      for (int nd = 0; nd < 4; nd++) {
        ao[((size_t)(b * 1024 + n) << 9) + h * 64 + nd * 16 + c] =
            f2b(acco[mi][nd][m] * invm);
      }
    }
  }
}

// ---------------- launch ----------------
extern "C" void kernel_launch(void* const* d_in, const int* in_sizes, int n_in,
                              void* d_out, int out_size, void* d_ws, size_t ws_size,
                              hipStream_t stream) {
  (void)in_sizes; (void)n_in; (void)out_size; (void)ws_size;
  const float* x  = (const float*)d_in[0];
  const float* Wq = (const float*)d_in[1];
  const float* bq = (const float*)d_in[2];
  const float* Wk = (const float*)d_in[3];
  const float* bk = (const float*)d_in[4];
  const float* Wv = (const float*)d_in[5];
  const float* bv = (const float*)d_in[6];
  const float* Wo = (const float*)d_in[7];
  const float* bo = (const float*)d_in[8];
  const float* pbias = (const float*)d_in[9];

  char* p = (char*)d_ws;
  unsigned short* xb  = (unsigned short*)p; p += (size_t)8192 * 512 * 2;
  unsigned short* WT  = (unsigned short*)p; p += (size_t)4 * 512 * 512 * 2;
  unsigned short* Qb  = (unsigned short*)p; p += (size_t)3 * 64 * 1024 * 64 * 2;
  unsigned short* AO  = (unsigned short*)p;

  unsigned short* WoT = WT + (size_t)3 * 512 * 512;
  unsigned short* Kb  = Qb + (size_t)64 * 1024 * 64;
  unsigned short* Vb  = Kb + (size_t)64 * 1024 * 64;  // V^T slab [bh][d][n]

  prep_k<<<4352, 256, 0, stream>>>(x, xb, Wq, Wk, Wv, Wo, WT);
  gemm_qkv_k<<<768, 256, 0, stream>>>(xb, WT, bq, bk, bv, Qb);
  attn_k<<<512, 256, 0, stream>>>(Qb, Kb, Vb, pbias, AO);
  gemm_o_k<<<256, 512, 0, stream>>>(AO, WoT, bo, (float*)d_out);
}